// Round 1
// baseline (447.787 us; speedup 1.0000x reference)
//
#include <hip/hip_runtime.h>
#include <hip/hip_bf16.h>
#include <cstdint>
#include <cstddef>

// ---------- types ----------
typedef __attribute__((ext_vector_type(8))) __bf16 bf16x8;
typedef __attribute__((ext_vector_type(4))) float f32x4;
typedef __attribute__((ext_vector_type(4))) unsigned short u16x4;

#define DEVINL static __device__ __forceinline__

DEVINL unsigned short f2bf(float x) {
  union { float f; unsigned u; } un; un.f = x;
  unsigned r = un.u + 0x7fffu + ((un.u >> 16) & 1u);
  return (unsigned short)(r >> 16);
}

DEVINL void gload16(const void* g, void* l) {
  __builtin_amdgcn_global_load_lds(
      (__attribute__((address_space(1))) void*)(void*)(uintptr_t)(const void*)g,
      (__attribute__((address_space(3))) void*)l, 16, 0, 0);
}

// ---------- sums: D1 = col sums, D2 = row sums of tilde [8192][8192] ----------
__global__ __launch_bounds__(256) void sums_kernel(const float* __restrict__ tilde,
                                                   float* __restrict__ D1,
                                                   float* __restrict__ D2) {
  const int t = threadIdx.x;
  float ca[8][4];
#pragma unroll
  for (int i = 0; i < 8; ++i)
#pragma unroll
    for (int j = 0; j < 4; ++j) ca[i][j] = 0.f;
  const int base_row = blockIdx.x * 32;
  for (int r = 0; r < 32; ++r) {
    const float4* rp = (const float4*)(tilde + (size_t)(base_row + r) * 8192);
    float rs = 0.f;
#pragma unroll
    for (int i = 0; i < 8; ++i) {
      float4 v = rp[t + i * 256];
      ca[i][0] += v.x; ca[i][1] += v.y; ca[i][2] += v.z; ca[i][3] += v.w;
      rs += (v.x + v.y) + (v.z + v.w);
    }
#pragma unroll
    for (int off = 32; off > 0; off >>= 1) rs += __shfl_down(rs, off, 64);
    if ((t & 63) == 0) atomicAdd(&D2[base_row + r], rs);
  }
#pragma unroll
  for (int i = 0; i < 8; ++i)
#pragma unroll
    for (int j = 0; j < 4; ++j)
      atomicAdd(&D1[(t + i * 256) * 4 + j], ca[i][j]);
}

// ---------- s[j] = sqrt(D1[j]*D2[j]) ----------
__global__ __launch_bounds__(256) void colscale_kernel(const float* __restrict__ D1,
                                                       const float* __restrict__ D2,
                                                       float* __restrict__ s) {
  int i = blockIdx.x * 256 + threadIdx.x;
  s[i] = sqrtf(D1[i] * D2[i]);
}

// ---------- A_bf16[i][j] = bf16(tilde[i][j] * s[j]) ----------
__global__ __launch_bounds__(256) void scale_convert(const float4* __restrict__ t4,
                                                     const float4* __restrict__ s4,
                                                     u16x4* __restrict__ out) {
  const size_t total = (size_t)8192 * 2048;
  const size_t stride = (size_t)gridDim.x * 256;
  for (size_t i = blockIdx.x * 256 + threadIdx.x; i < total; i += stride) {
    int c4 = (int)(i & 2047);
    float4 v = t4[i];
    float4 sc = s4[c4];
    u16x4 o;
    o[0] = f2bf(v.x * sc.x);
    o[1] = f2bf(v.y * sc.y);
    o[2] = f2bf(v.z * sc.z);
    o[3] = f2bf(v.w * sc.w);
    out[i] = o;
  }
}

// ---------- fp32 -> bf16 convert ----------
__global__ __launch_bounds__(256) void convert_bf16(const float4* __restrict__ in,
                                                    u16x4* __restrict__ out, int n4) {
  const int stride = gridDim.x * 256;
  for (int i = blockIdx.x * 256 + threadIdx.x; i < n4; i += stride) {
    float4 v = in[i];
    u16x4 o;
    o[0] = f2bf(v.x); o[1] = f2bf(v.y); o[2] = f2bf(v.z); o[3] = f2bf(v.w);
    out[i] = o;
  }
}

// ---------- transpose + convert: out[c][r] = bf16(in[r][c]) ----------
__global__ __launch_bounds__(256) void transpose_cvt(const float* __restrict__ in,
                                                     unsigned short* __restrict__ out,
                                                     int R, int C) {
  int o = blockIdx.x * 256 + threadIdx.x;
  if (o >= R * C) return;
  int c = o / R, r = o - c * R;
  out[o] = f2bf(in[(size_t)r * C + c]);
}

// ---------- tiled MFMA GEMM: C[M,N] = A[M,K] @ B[K,N], BT given as [N][K] ----------
// EPI: 0 = bf16 out, +bias[row]; 1 = bf16 out, relu; 2 = f32 partial out (split-K)
template <int BM, int BN, int EPI>
__global__ __launch_bounds__(256) void gemm_bt(
    const unsigned short* __restrict__ A,   // [M][K] bf16 row-major
    const unsigned short* __restrict__ BT,  // [N][K] bf16 row-major
    void* __restrict__ C,
    const float* __restrict__ bias,
    int M, int N, int K, int kChunk, int ldc) {
  constexpr int WTM = BM / 2, WTN = BN / 2;
  constexpr int MR = WTM / 16, NR = WTN / 16;
  constexpr int AIT = BM * 4 / 256;  // 16B loads per thread for A tile
  constexpr int BIT = BN * 4 / 256;

  __shared__ unsigned short As[BM * 32];
  __shared__ unsigned short Bs[BN * 32];

  const int t = threadIdx.x;
  const int lane = t & 63, wave = t >> 6;
  const int wr = wave >> 1, wc = wave & 1;
  const int bm = blockIdx.x, bn = blockIdx.y, bz = blockIdx.z;
  const int row0 = bm * BM, col0 = bn * BN;
  const int kbeg = bz * kChunk, kend = kbeg + kChunk;
  const int lrow = lane & 15;
  const int lk = (lane >> 4) * 8;

  f32x4 acc[MR][NR];
#pragma unroll
  for (int m = 0; m < MR; ++m)
#pragma unroll
    for (int n = 0; n < NR; ++n) acc[m][n] = (f32x4){0.f, 0.f, 0.f, 0.f};

  for (int k0 = kbeg; k0 < kend; k0 += 32) {
#pragma unroll
    for (int i = 0; i < AIT; ++i) {
      int flat = i * 256 + t;
      int r = flat >> 2, ko = (flat & 3) * 8;
      gload16(A + (size_t)(row0 + r) * K + k0 + ko, As + (size_t)flat * 8);
    }
#pragma unroll
    for (int i = 0; i < BIT; ++i) {
      int flat = i * 256 + t;
      int r = flat >> 2, ko = (flat & 3) * 8;
      gload16(BT + (size_t)(col0 + r) * K + k0 + ko, Bs + (size_t)flat * 8);
    }
    __syncthreads();

    bf16x8 af[MR], bfr[NR];
#pragma unroll
    for (int m = 0; m < MR; ++m)
      af[m] = *(const bf16x8*)&As[(wr * WTM + m * 16 + lrow) * 32 + lk];
#pragma unroll
    for (int n = 0; n < NR; ++n)
      bfr[n] = *(const bf16x8*)&Bs[(wc * WTN + n * 16 + lrow) * 32 + lk];
#pragma unroll
    for (int m = 0; m < MR; ++m)
#pragma unroll
      for (int n = 0; n < NR; ++n)
        acc[m][n] = __builtin_amdgcn_mfma_f32_16x16x32_bf16(af[m], bfr[n], acc[m][n], 0, 0, 0);
    __syncthreads();
  }

  const int r0 = row0 + wr * WTM, c0 = col0 + wc * WTN;
  if constexpr (EPI == 2) {
    float* Cf = (float*)C + (size_t)bz * M * ldc;
#pragma unroll
    for (int m = 0; m < MR; ++m)
#pragma unroll
      for (int n = 0; n < NR; ++n)
#pragma unroll
        for (int j = 0; j < 4; ++j) {
          int row = r0 + m * 16 + (lane >> 4) * 4 + j;
          int col = c0 + n * 16 + lrow;
          Cf[(size_t)row * ldc + col] = acc[m][n][j];
        }
  } else {
    unsigned short* Cb = (unsigned short*)C;
#pragma unroll
    for (int m = 0; m < MR; ++m)
#pragma unroll
      for (int n = 0; n < NR; ++n)
#pragma unroll
        for (int j = 0; j < 4; ++j) {
          int row = r0 + m * 16 + (lane >> 4) * 4 + j;
          int col = c0 + n * 16 + lrow;
          float v = acc[m][n][j];
          if constexpr (EPI == 0) v += bias[row];
          if constexpr (EPI == 1) v = v > 0.f ? v : 0.f;
          Cb[(size_t)row * ldc + col] = f2bf(v);
        }
  }
}

// ---------- reduce split-K partials ----------
__global__ __launch_bounds__(256) void reduce_parts(const float* __restrict__ part,
                                                    float* __restrict__ out,
                                                    int total, int splits) {
  int i = blockIdx.x * 256 + threadIdx.x;
  if (i < total) {
    float s = 0.f;
    for (int z = 0; z < splits; ++z) s += part[(size_t)z * total + i];
    out[i] = s;
  }
}

// ---------- launch ----------
extern "C" void kernel_launch(void* const* d_in, const int* in_sizes, int n_in,
                              void* d_out, int out_size, void* d_ws, size_t ws_size,
                              hipStream_t stream) {
  const float* X     = (const float*)d_in[0];
  const float* tilde = (const float*)d_in[1];
  const float* W1    = (const float*)d_in[2];
  const float* b1    = (const float*)d_in[3];
  const float* W2    = (const float*)d_in[4];
  const float* b2    = (const float*)d_in[5];
  float* out = (float*)d_out;

  constexpr int N = 8192, F = 1024, H = 512, Cc = 64;

  char* ws = (char*)d_ws;
  size_t off = 0;
  auto alloc = [&](size_t bytes) {
    char* p = ws + off;
    off += (bytes + 255) & ~(size_t)255;
    return p;
  };
  unsigned short* Abf  = (unsigned short*)alloc((size_t)N * N * 2);       // 128 MB
  unsigned short* Xbf  = (unsigned short*)alloc((size_t)N * F * 2);       // 16 MB
  unsigned short* W1T  = (unsigned short*)alloc((size_t)H * F * 2);       // 1 MB
  unsigned short* XW1T = (unsigned short*)alloc((size_t)H * N * 2);       // 8 MB
  unsigned short* hbuf = (unsigned short*)alloc((size_t)N * H * 2);       // 8 MB
  unsigned short* W2T  = (unsigned short*)alloc((size_t)Cc * H * 2);      // 64 KB
  unsigned short* ZT   = (unsigned short*)alloc((size_t)Cc * N * 2);      // 1 MB
  float* D1 = (float*)alloc(N * 4);
  float* D2 = (float*)alloc(N * 4);
  float* sv = (float*)alloc(N * 4);
  // split-K partials overlap Xbf (dead after gemm1): 8*8192*64*4 = 16 MB
  float* part = (float*)Xbf;

  hipMemsetAsync(D1, 0, N * 4, stream);
  hipMemsetAsync(D2, 0, N * 4, stream);

  // normalization
  sums_kernel<<<256, 256, 0, stream>>>(tilde, D1, D2);
  colscale_kernel<<<N / 256, 256, 0, stream>>>(D1, D2, sv);
  scale_convert<<<4096, 256, 0, stream>>>((const float4*)tilde, (const float4*)sv, (u16x4*)Abf);

  // operand prep
  convert_bf16<<<2048, 256, 0, stream>>>((const float4*)X, (u16x4*)Xbf, N * F / 4);
  transpose_cvt<<<(F * H) / 256, 256, 0, stream>>>(W1, W1T, F, H);
  transpose_cvt<<<(H * Cc) / 256, 256, 0, stream>>>(W2, W2T, H, Cc);

  // gemm1: XW1^T[H][N] = W1T[H][F] @ X^T   (BT = Xbf [N][F]), +b1
  gemm_bt<128, 128, 0><<<dim3(H / 128, N / 128, 1), 256, 0, stream>>>(
      W1T, Xbf, XW1T, b1, H, N, F, F, N);
  // gemm2: h[N][H] = A[N][N] @ XW1 (BT = XW1T [H][N]), relu
  gemm_bt<128, 128, 1><<<dim3(N / 128, H / 128, 1), 256, 0, stream>>>(
      Abf, XW1T, hbuf, nullptr, N, H, N, N, H);
  // gemm3: Z^T[C][N] = W2T[C][H] @ h^T (BT = h [N][H]), +b2
  gemm_bt<64, 128, 0><<<dim3(Cc / 64, N / 128, 1), 256, 0, stream>>>(
      W2T, hbuf, ZT, b2, Cc, N, H, H, N);
  // gemm4: out[N][C] = A[N][N] @ Z (BT = ZT [C][N]), split-K=8, f32 partials
  gemm_bt<128, 64, 2><<<dim3(N / 128, 1, 8), 256, 0, stream>>>(
      Abf, ZT, part, nullptr, N, Cc, N, N / 8, Cc);
  reduce_parts<<<(N * Cc) / 256, 256, 0, stream>>>(part, out, N * Cc, 8);
}

// Round 2
// 365.419 us; speedup vs baseline: 1.2254x; 1.2254x over previous
//
#include <hip/hip_runtime.h>
#include <hip/hip_bf16.h>
#include <cstdint>
#include <cstddef>

// ---------- types ----------
typedef __attribute__((ext_vector_type(8))) __bf16 bf16x8;
typedef __attribute__((ext_vector_type(4))) float f32x4;
typedef __attribute__((ext_vector_type(4))) unsigned short u16x4;

#define DEVINL static __device__ __forceinline__

DEVINL unsigned short f2bf(float x) {
  union { float f; unsigned u; } un; un.f = x;
  unsigned r = un.u + 0x7fffu + ((un.u >> 16) & 1u);
  return (unsigned short)(r >> 16);
}

DEVINL void gload16(const void* g, void* l) {
  __builtin_amdgcn_global_load_lds(
      (__attribute__((address_space(1))) void*)(void*)(uintptr_t)(const void*)g,
      (__attribute__((address_space(3))) void*)l, 16, 0, 0);
}

// ---------- fused: row/col sums of tilde + convert tilde -> bf16 ----------
// grid 512 x 16 rows each; 8192 cols; 256 threads
__global__ __launch_bounds__(256) void sums_convert(const float* __restrict__ tilde,
                                                    float* __restrict__ D1,
                                                    float* __restrict__ D2,
                                                    u16x4* __restrict__ Tbf) {
  const int t = threadIdx.x;
  float ca[8][4];
#pragma unroll
  for (int i = 0; i < 8; ++i)
#pragma unroll
    for (int j = 0; j < 4; ++j) ca[i][j] = 0.f;
  const int base_row = blockIdx.x * 16;
  for (int r = 0; r < 16; ++r) {
    const size_t rowoff = (size_t)(base_row + r) * 2048;  // float4 units
    const float4* rp = (const float4*)tilde + rowoff;
    u16x4* op = Tbf + rowoff;
    float rs = 0.f;
#pragma unroll
    for (int i = 0; i < 8; ++i) {
      float4 v = rp[t + i * 256];
      ca[i][0] += v.x; ca[i][1] += v.y; ca[i][2] += v.z; ca[i][3] += v.w;
      rs += (v.x + v.y) + (v.z + v.w);
      u16x4 o;
      o[0] = f2bf(v.x); o[1] = f2bf(v.y); o[2] = f2bf(v.z); o[3] = f2bf(v.w);
      op[t + i * 256] = o;
    }
#pragma unroll
    for (int off = 32; off > 0; off >>= 1) rs += __shfl_down(rs, off, 64);
    if ((t & 63) == 0) atomicAdd(&D2[base_row + r], rs);
  }
#pragma unroll
  for (int i = 0; i < 8; ++i)
#pragma unroll
    for (int j = 0; j < 4; ++j)
      atomicAdd(&D1[(t + i * 256) * 4 + j], ca[i][j]);
}

// ---------- s[j] = sqrt(D1[j]*D2[j]) ----------
__global__ __launch_bounds__(256) void colscale_kernel(const float* __restrict__ D1,
                                                       const float* __restrict__ D2,
                                                       float* __restrict__ s) {
  int i = blockIdx.x * 256 + threadIdx.x;
  s[i] = sqrtf(D1[i] * D2[i]);
}

// ---------- fp32 -> bf16 convert ----------
__global__ __launch_bounds__(256) void convert_bf16(const float4* __restrict__ in,
                                                    u16x4* __restrict__ out, int n4) {
  const int stride = gridDim.x * 256;
  for (int i = blockIdx.x * 256 + threadIdx.x; i < n4; i += stride) {
    float4 v = in[i];
    u16x4 o;
    o[0] = f2bf(v.x); o[1] = f2bf(v.y); o[2] = f2bf(v.z); o[3] = f2bf(v.w);
    out[i] = o;
  }
}

// ---------- transpose + convert: out[c][r] = bf16(in[r][c]) ----------
__global__ __launch_bounds__(256) void transpose_cvt(const float* __restrict__ in,
                                                     unsigned short* __restrict__ out,
                                                     int R, int C) {
  int o = blockIdx.x * 256 + threadIdx.x;
  if (o >= R * C) return;
  int c = o / R, r = o - c * R;
  out[o] = f2bf(in[(size_t)r * C + c]);
}

// ---------- tiled MFMA GEMM: C[M,N] = A[M,K] @ B[K,N], BT given as [N][K] ----------
// EPI: 1 = bf16 out + relu; 2 = f32 partial out (split-K); 3 = bf16 out, (acc+bias[row])*cs[col]
template <int BM, int BN, int EPI>
__global__ __launch_bounds__(256) void gemm_bt(
    const unsigned short* __restrict__ A,   // [M][K] bf16 row-major
    const unsigned short* __restrict__ BT,  // [N][K] bf16 row-major
    void* __restrict__ C,
    const float* __restrict__ bias,
    const float* __restrict__ cs,
    int M, int N, int K, int kChunk, int ldc) {
  constexpr int WTM = BM / 2, WTN = BN / 2;
  constexpr int MR = WTM / 16, NR = WTN / 16;
  constexpr int AIT = BM * 4 / 256;
  constexpr int BIT = BN * 4 / 256;

  __shared__ unsigned short As[BM * 32];
  __shared__ unsigned short Bs[BN * 32];

  const int t = threadIdx.x;
  const int lane = t & 63, wave = t >> 6;
  const int wr = wave >> 1, wc = wave & 1;
  const int bm = blockIdx.x, bn = blockIdx.y, bz = blockIdx.z;
  const int row0 = bm * BM, col0 = bn * BN;
  const int kbeg = bz * kChunk, kend = kbeg + kChunk;
  const int lrow = lane & 15;
  const int lk = (lane >> 4) * 8;

  f32x4 acc[MR][NR];
#pragma unroll
  for (int m = 0; m < MR; ++m)
#pragma unroll
    for (int n = 0; n < NR; ++n) acc[m][n] = (f32x4){0.f, 0.f, 0.f, 0.f};

  for (int k0 = kbeg; k0 < kend; k0 += 32) {
#pragma unroll
    for (int i = 0; i < AIT; ++i) {
      int flat = i * 256 + t;
      int r = flat >> 2, ko = (flat & 3) * 8;
      gload16(A + (size_t)(row0 + r) * K + k0 + ko, As + (size_t)flat * 8);
    }
#pragma unroll
    for (int i = 0; i < BIT; ++i) {
      int flat = i * 256 + t;
      int r = flat >> 2, ko = (flat & 3) * 8;
      gload16(BT + (size_t)(col0 + r) * K + k0 + ko, Bs + (size_t)flat * 8);
    }
    __syncthreads();

    bf16x8 af[MR], bfr[NR];
#pragma unroll
    for (int m = 0; m < MR; ++m)
      af[m] = *(const bf16x8*)&As[(wr * WTM + m * 16 + lrow) * 32 + lk];
#pragma unroll
    for (int n = 0; n < NR; ++n)
      bfr[n] = *(const bf16x8*)&Bs[(wc * WTN + n * 16 + lrow) * 32 + lk];
#pragma unroll
    for (int m = 0; m < MR; ++m)
#pragma unroll
      for (int n = 0; n < NR; ++n)
        acc[m][n] = __builtin_amdgcn_mfma_f32_16x16x32_bf16(af[m], bfr[n], acc[m][n], 0, 0, 0);
    __syncthreads();
  }

  const int r0 = row0 + wr * WTM, c0 = col0 + wc * WTN;
  if constexpr (EPI == 2) {
    float* Cf = (float*)C + (size_t)bz * M * ldc;
#pragma unroll
    for (int m = 0; m < MR; ++m)
#pragma unroll
      for (int n = 0; n < NR; ++n)
#pragma unroll
        for (int j = 0; j < 4; ++j) {
          int row = r0 + m * 16 + (lane >> 4) * 4 + j;
          int col = c0 + n * 16 + lrow;
          Cf[(size_t)row * ldc + col] = acc[m][n][j];
        }
  } else {
    unsigned short* Cb = (unsigned short*)C;
#pragma unroll
    for (int m = 0; m < MR; ++m)
#pragma unroll
      for (int n = 0; n < NR; ++n)
#pragma unroll
        for (int j = 0; j < 4; ++j) {
          int row = r0 + m * 16 + (lane >> 4) * 4 + j;
          int col = c0 + n * 16 + lrow;
          float v = acc[m][n][j];
          if constexpr (EPI == 1) v = v > 0.f ? v : 0.f;
          if constexpr (EPI == 3) v = (v + bias[row]) * cs[col];
          Cb[(size_t)row * ldc + col] = f2bf(v);
        }
  }
}

// ---------- reduce split-K partials -> relu -> bf16 ----------
__global__ __launch_bounds__(256) void reduce_relu_bf16(const float4* __restrict__ part,
                                                        u16x4* __restrict__ out,
                                                        int total4, int splits) {
  const int stride = gridDim.x * 256;
  for (int i = blockIdx.x * 256 + threadIdx.x; i < total4; i += stride) {
    float4 s = part[i];
    for (int z = 1; z < splits; ++z) {
      float4 v = part[(size_t)z * total4 + i];
      s.x += v.x; s.y += v.y; s.z += v.z; s.w += v.w;
    }
    u16x4 o;
    o[0] = f2bf(s.x > 0.f ? s.x : 0.f);
    o[1] = f2bf(s.y > 0.f ? s.y : 0.f);
    o[2] = f2bf(s.z > 0.f ? s.z : 0.f);
    o[3] = f2bf(s.w > 0.f ? s.w : 0.f);
    out[i] = o;
  }
}

// ---------- reduce split-K partials -> f32 ----------
__global__ __launch_bounds__(256) void reduce_f32(const float4* __restrict__ part,
                                                  float4* __restrict__ out,
                                                  int total4, int splits) {
  const int stride = gridDim.x * 256;
  for (int i = blockIdx.x * 256 + threadIdx.x; i < total4; i += stride) {
    float4 s = part[i];
    for (int z = 1; z < splits; ++z) {
      float4 v = part[(size_t)z * total4 + i];
      s.x += v.x; s.y += v.y; s.z += v.z; s.w += v.w;
    }
    out[i] = s;
  }
}

// ---------- launch ----------
extern "C" void kernel_launch(void* const* d_in, const int* in_sizes, int n_in,
                              void* d_out, int out_size, void* d_ws, size_t ws_size,
                              hipStream_t stream) {
  const float* X     = (const float*)d_in[0];
  const float* tilde = (const float*)d_in[1];
  const float* W1    = (const float*)d_in[2];
  const float* b1    = (const float*)d_in[3];
  const float* W2    = (const float*)d_in[4];
  const float* b2    = (const float*)d_in[5];
  float* out = (float*)d_out;

  constexpr int N = 8192, F = 1024, H = 512, Cc = 64;

  char* ws = (char*)d_ws;
  size_t off = 0;
  auto alloc = [&](size_t bytes) {
    char* p = ws + off;
    off += (bytes + 255) & ~(size_t)255;
    return p;
  };
  // persistent-ish region
  unsigned short* Tbf  = (unsigned short*)alloc((size_t)N * N * 2);   // 128 MB (live thru gemm4)
  unsigned short* XW1T = (unsigned short*)alloc((size_t)H * N * 2);   // 8 MB  (dead after gemm2)
  unsigned short* hbuf = (unsigned short*)alloc((size_t)N * H * 2);   // 8 MB  (dead after gemm3)
  unsigned short* ZT   = (unsigned short*)alloc((size_t)Cc * N * 2);  // 1 MB  (dead after gemm4)
  unsigned short* W2T  = (unsigned short*)alloc((size_t)Cc * H * 2);  // 64 KB
  float* D1 = (float*)alloc(N * 4);
  float* D2 = (float*)alloc(N * 4);
  float* sv = (float*)alloc(N * 4);
  // scratch zone (serial reuse): [Xbf 16MB | W1T 1MB] -> [part2 64MB] -> [part4 16MB]
  const size_t scratch_base = off;
  unsigned short* Xbf = (unsigned short*)(ws + scratch_base);                      // 16 MB
  unsigned short* W1T = (unsigned short*)(ws + scratch_base + (size_t)N * F * 2);  // 1 MB
  float* part2 = (float*)(ws + scratch_base);  // 4 * 8192*512*4 = 64 MB
  float* part4 = (float*)(ws + scratch_base);  // 8 * 8192*64*4  = 16 MB

  const size_t need_split = scratch_base + (size_t)4 * N * H * 4;     // ~209 MB
  const bool splitk2 = ws_size >= need_split;

  hipMemsetAsync(D1, 0, N * 4, stream);
  hipMemsetAsync(D2, 0, N * 4, stream);

  // fused sums + tilde->bf16 (A never materialized; scale folded into later epilogues)
  sums_convert<<<512, 256, 0, stream>>>(tilde, D1, D2, (u16x4*)Tbf);
  colscale_kernel<<<N / 256, 256, 0, stream>>>(D1, D2, sv);

  // operand prep
  convert_bf16<<<2048, 256, 0, stream>>>((const float4*)X, (u16x4*)Xbf, N * F / 4);
  transpose_cvt<<<(F * H) / 256, 256, 0, stream>>>(W1, W1T, F, H);
  transpose_cvt<<<(H * Cc) / 256, 256, 0, stream>>>(W2, W2T, H, Cc);

  // gemm1: XW1T[H][N] = W1T[H][F] @ X^T, epi: (acc+b1[row])*s[col]
  gemm_bt<128, 128, 3><<<dim3(H / 128, N / 128, 1), 256, 0, stream>>>(
      W1T, Xbf, XW1T, b1, sv, H, N, F, F, N);

  // gemm2: h[N][H] = tilde_bf @ (s*XW1) (BT = XW1T), relu.  split-K=4 if ws allows.
  if (splitk2) {
    gemm_bt<128, 128, 2><<<dim3(N / 128, H / 128, 4), 256, 0, stream>>>(
        Tbf, XW1T, part2, nullptr, nullptr, N, H, N, N / 4, H);
    reduce_relu_bf16<<<1024, 256, 0, stream>>>((const float4*)part2, (u16x4*)hbuf,
                                               N * H / 4, 4);
  } else {
    gemm_bt<128, 128, 1><<<dim3(N / 128, H / 128, 1), 256, 0, stream>>>(
        Tbf, XW1T, hbuf, nullptr, nullptr, N, H, N, N, H);
  }

  // gemm3: ZT[C][N] = W2T[C][H] @ h^T (BT = hbuf), epi: (acc+b2[row])*s[col]
  gemm_bt<64, 128, 3><<<dim3(Cc / 64, N / 128, 1), 256, 0, stream>>>(
      W2T, hbuf, ZT, b2, sv, Cc, N, H, H, N);

  // gemm4: out[N][C] = tilde_bf @ (s*Z) (BT = ZT), split-K=8, f32 partials
  gemm_bt<128, 64, 2><<<dim3(N / 128, 1, 8), 256, 0, stream>>>(
      Tbf, ZT, part4, nullptr, nullptr, N, Cc, N, N / 8, Cc);
  reduce_f32<<<512, 256, 0, stream>>>((const float4*)part4, (float4*)out, N * Cc / 4, 8);
}